// Round 2
// baseline (1768.467 us; speedup 1.0000x reference)
//
#include <hip/hip_runtime.h>

#define H_ 1024
#define W_ 1024
#define BATCH_ 4
#define CIN_ 32
#define COUT_ 32
#define KSZ_ 9

#define TW 16
#define TH 32                  // output rows per block, two 16-row chunks
#define HROWS 38               // TH + 6 halo rows
#define PITCH 22               // stored halo cols (exactly what compute reads)
#define QSTRIDE (HROWS * PITCH + 1)   // uint4 units per channel-quad (+1 stagger)
#define NTAPS 29

typedef __attribute__((ext_vector_type(8))) short short8;
typedef __attribute__((ext_vector_type(4))) float f32x4;

struct Tap { int dy, dx; };

// taps with dy^2+dx^2 <= 9 (disk support of psi)
#define TAPS_LIST \
  {-3,0}, \
  {-2,-2},{-2,-1},{-2,0},{-2,1},{-2,2}, \
  {-1,-2},{-1,-1},{-1,0},{-1,1},{-1,2}, \
  {0,-3},{0,-2},{0,-1},{0,0},{0,1},{0,2},{0,3}, \
  {1,-2},{1,-1},{1,0},{1,1},{1,2}, \
  {2,-2},{2,-1},{2,0},{2,1},{2,2}, \
  {3,0}

__device__ const Tap g_taps[NTAPS] = { TAPS_LIST };

__device__ __forceinline__ unsigned short f2bf(float f) {
    unsigned int u = __builtin_bit_cast(unsigned int, f);
    u = (u + 0x7FFFu + ((u >> 16) & 1u)) >> 16;   // RNE
    return (unsigned short)u;
}

__device__ __forceinline__ unsigned cvt_pk_bf16(float lo, float hi) {
    unsigned r;
    asm("v_cvt_pk_bf16_f32 %0, %1, %2" : "=v"(r) : "v"(lo), "v"(hi));
    return r;
}

// kw[t][q][oc][j]  (j = ic within quad, ic = q*8+j), flat bf16, 29*1024 elems.
__global__ void build_kw(const float* __restrict__ weight,
                         const float* __restrict__ psi,
                         unsigned short* __restrict__ kw) {
    int t = blockIdx.x;
    int a = g_taps[t].dy + 3;
    int bb = g_taps[t].dx + 3;
    float pv[KSZ_];
#pragma unroll
    for (int k = 0; k < KSZ_; ++k) pv[k] = psi[k * 49 + a * 7 + bb];
    for (int e = threadIdx.x; e < 1024; e += blockDim.x) {
        int q = e >> 8, rem = e & 255, oc = rem >> 3, j = rem & 7;
        int ic = q * 8 + j;
        float acc = 0.f;
#pragma unroll
        for (int k = 0; k < KSZ_; ++k) acc += pv[k] * weight[(oc * CIN_ + ic) * KSZ_ + k];
        kw[t * 1024 + e] = f2bf(acc);
    }
}

template<int T0, int T1>
__device__ __forceinline__ void do_taps(const uint4* const (&bq)[4],
                                        const uint4* __restrict__ kw4,
                                        int quad, int p16,
                                        f32x4 (&acc)[4][2]) {
    constexpr Tap taps[NTAPS] = { TAPS_LIST };
#pragma unroll
    for (int t = T0; t < T1; ++t) {
        short8 a0 = __builtin_bit_cast(short8, kw4[t * 128 + quad * 32 + p16]);
        short8 a1 = __builtin_bit_cast(short8, kw4[t * 128 + quad * 32 + 16 + p16]);
#pragma unroll
        for (int g = 0; g < 4; ++g) {
            short8 bf = __builtin_bit_cast(short8, bq[g][taps[t].dy * PITCH + taps[t].dx + 69]);
            acc[g][0] = __builtin_amdgcn_mfma_f32_16x16x32_bf16(a0, bf, acc[g][0], 0, 0, 0);
            acc[g][1] = __builtin_amdgcn_mfma_f32_16x16x32_bf16(a1, bf, acc[g][1], 0, 0, 0);
        }
    }
}

__global__ __launch_bounds__(256, 3)
void dconv(const float* __restrict__ x, const uint4* __restrict__ kw4,
           const float* __restrict__ bias, float* __restrict__ out) {
    // xt[q][row][col]: uint4 = 8 bf16 channels (ic q*8..q*8+7) of one pixel
    __shared__ uint4 xt[4 * QSTRIDE];   // 53,568 B -> 3 blocks/CU

    const int tid = threadIdx.x;
    const unsigned bid = blockIdx.x;
    const int txt = bid & 63;
    const int tyt = (bid >> 6) & 31;
    const int b   = bid >> 11;
    const int x0 = txt * TW, y0 = tyt * TH;
    const size_t plane = (size_t)H_ * W_;

    // ---- generic stager: item = (q, row, c4); loads 8ch x 4px, packs, clip-stores ----
    auto stage_item = [&](int q, int row, int c4) {
        int gy  = y0 + row - 3;
        int gx0 = x0 + c4 * 4 - 4;     // loads span lds cols [c4*4-1 .. c4*4+2]
        bool rowin = (gy >= 0) & (gy < H_);
        const float* cb = x + (size_t)(b * CIN_ + q * 8) * plane
                            + (size_t)(rowin ? gy : 0) * W_;
        float v[8][4];
        if (rowin & (gx0 >= 0) & (gx0 + 4 <= W_)) {
            const float* p0 = cb + gx0;
#pragma unroll
            for (int j = 0; j < 8; ++j) {
                const float4 f = *reinterpret_cast<const float4*>(p0 + (size_t)j * plane);
                v[j][0] = f.x; v[j][1] = f.y; v[j][2] = f.z; v[j][3] = f.w;
            }
        } else {
#pragma unroll
            for (int j = 0; j < 8; ++j)
#pragma unroll
                for (int c = 0; c < 4; ++c) {
                    int gx = gx0 + c;
                    bool inb = rowin & (gx >= 0) & (gx < W_);
                    v[j][c] = inb ? cb[(size_t)j * plane + gx] : 0.f;
                }
        }
        uint4* dst = &xt[q * QSTRIDE + row * PITCH];
#pragma unroll
        for (int c = 0; c < 4; ++c) {
            int col = c4 * 4 + c - 1;
            if (col >= 0 && col < PITCH) {
                uint4 pk;
                pk.x = cvt_pk_bf16(v[0][c], v[1][c]);
                pk.y = cvt_pk_bf16(v[2][c], v[3][c]);
                pk.z = cvt_pk_bf16(v[4][c], v[5][c]);
                pk.w = cvt_pk_bf16(v[6][c], v[7][c]);
                dst[col] = pk;
            }
        }
    };

    // ---- prologue: stage halo rows 0..21 (22 rows, chunk-0 window) ----
    {
        auto do_it = [&](int it) {
            int q = it / 132, rem = it - q * 132;
            stage_item(q, rem / 6, rem - (rem / 6) * 6);
        };
        do_it(tid);
        do_it(tid + 256);
        if (tid < 16) do_it(tid + 512);
    }
    __syncthreads();

    // ---- prefetch state: 8-row batch in registers (192 active threads) ----
    const bool pact = tid < 192;
    int pq = 0, prow = 0, pc4 = 0;
    float pv[8][4];
    auto pf_issue = [&](int h) {
        if (!pact) return;
        pq = tid / 48;
        int rem = tid - pq * 48;
        int r8 = rem / 6;
        pc4 = rem - r8 * 6;
        prow = 22 + 8 * h + r8;
        int gy  = y0 + prow - 3;       // >= 19, only bottom clamp needed
        int gx0 = x0 + pc4 * 4 - 4;
        bool rowin = gy < H_;
        const float* cb = x + (size_t)(b * CIN_ + pq * 8) * plane
                            + (size_t)(rowin ? gy : 0) * W_;
        if (rowin & (gx0 >= 0) & (gx0 + 4 <= W_)) {
            const float* p0 = cb + gx0;
#pragma unroll
            for (int j = 0; j < 8; ++j) {
                const float4 f = *reinterpret_cast<const float4*>(p0 + (size_t)j * plane);
                pv[j][0] = f.x; pv[j][1] = f.y; pv[j][2] = f.z; pv[j][3] = f.w;
            }
        } else {
#pragma unroll
            for (int j = 0; j < 8; ++j)
#pragma unroll
                for (int c = 0; c < 4; ++c) {
                    int gx = gx0 + c;
                    bool inb = rowin & (gx >= 0) & (gx < W_);
                    pv[j][c] = inb ? cb[(size_t)j * plane + gx] : 0.f;
                }
        }
    };
    auto pf_commit = [&]() {
        if (!pact) return;
        uint4* dst = &xt[pq * QSTRIDE + prow * PITCH];
#pragma unroll
        for (int c = 0; c < 4; ++c) {
            int col = pc4 * 4 + c - 1;
            if (col >= 0 && col < PITCH) {
                uint4 pk;
                pk.x = cvt_pk_bf16(pv[0][c], pv[1][c]);
                pk.y = cvt_pk_bf16(pv[2][c], pv[3][c]);
                pk.z = cvt_pk_bf16(pv[4][c], pv[5][c]);
                pk.w = cvt_pk_bf16(pv[6][c], pv[7][c]);
                dst[col] = pk;
            }
        }
    };

    // ---- compute setup ----
    const int wv = tid >> 6, lane = tid & 63;
    const int p16 = lane & 15, quad = lane >> 4;

    float bv[2][4];
#pragma unroll
    for (int h = 0; h < 2; ++h)
#pragma unroll
        for (int i = 0; i < 4; ++i) bv[h][i] = bias[h * 16 + quad * 4 + i];

    float* ob = out + (size_t)b * COUT_ * plane;
    const uint4* bq[4];
    f32x4 acc[4][2];

    auto set_bq = [&](int c) {
#pragma unroll
        for (int g = 0; g < 4; ++g)
            bq[g] = &xt[quad * QSTRIDE] + (c * 16 + wv * 4 + g + 3) * PITCH + (p16 + 3) - 69;
    };
    auto zero_acc = [&]() {
#pragma unroll
        for (int g = 0; g < 4; ++g) {
            acc[g][0] = f32x4{0.f, 0.f, 0.f, 0.f};
            acc[g][1] = f32x4{0.f, 0.f, 0.f, 0.f};
        }
    };
    auto store_chunk = [&](int c) {
#pragma unroll
        for (int g = 0; g < 4; ++g) {
            int gy = y0 + c * 16 + wv * 4 + g;
#pragma unroll
            for (int h = 0; h < 2; ++h)
#pragma unroll
                for (int i = 0; i < 4; ++i) {
                    int oc = h * 16 + quad * 4 + i;
                    ob[(size_t)oc * plane + (size_t)gy * W_ + x0 + p16] = acc[g][h][i] + bv[h][i];
                }
        }
    };

    // ---- chunk 0: compute overlapped with chunk-1 prefetch (2 x 8 rows) ----
    set_bq(0);
    zero_acc();
    pf_issue(0);                 // rows 22..29 in flight
    do_taps<0, 15>(bq, kw4, quad, p16, acc);
    pf_commit();                 // waitcnt + pack + ds_write rows 22..29
    pf_issue(1);                 // rows 30..37 in flight
    do_taps<15, NTAPS>(bq, kw4, quad, p16, acc);
    pf_commit();                 // rows 30..37 written
    store_chunk(0);
    __syncthreads();

    // ---- chunk 1 ----
    set_bq(1);
    zero_acc();
    do_taps<0, NTAPS>(bq, kw4, quad, p16, acc);
    store_chunk(1);
}

extern "C" void kernel_launch(void* const* d_in, const int* in_sizes, int n_in,
                              void* d_out, int out_size, void* d_ws, size_t ws_size,
                              hipStream_t stream) {
    const float* x      = (const float*)d_in[0];
    const float* weight = (const float*)d_in[1];
    const float* bias   = (const float*)d_in[2];
    const float* psi    = (const float*)d_in[3];
    float* out = (float*)d_out;
    unsigned short* kw = (unsigned short*)d_ws;   // 29*1024 bf16 = 59,392 B

    hipLaunchKernelGGL(build_kw, dim3(NTAPS), dim3(256), 0, stream, weight, psi, kw);
    hipLaunchKernelGGL(dconv, dim3(BATCH_ * (H_ / TH) * (W_ / TW)), dim3(256), 0, stream,
                       x, (const uint4*)kw, bias, out);
    (void)in_sizes; (void)n_in; (void)out_size; (void)ws_size;
}